// Round 17
// baseline (7842.883 us; speedup 1.0000x reference)
//
#include <hip/hip_runtime.h>

typedef __attribute__((ext_vector_type(4))) float f32x4;
typedef __attribute__((ext_vector_type(8))) __bf16 bf16x8;
typedef __attribute__((ext_vector_type(4))) __bf16 bf16x4;
typedef __attribute__((ext_vector_type(2))) __bf16 bf16x2;
typedef __attribute__((ext_vector_type(8))) unsigned short u16x8;

#define NB 512      // batch
#define TT 44       // t
#define S3 132      // 3*t
#define CC 512      // C
#define NH 8        // heads
#define NL 8        // layers
#define NV 1000     // vocab
#define VP 1024     // padded vocab
#define HID 2048
#define OH 768
#define WINW 30
#define QKVN 1536   // fused q,k,v output width

#define HROWS (NB*TT)         // 22528 total head rows

// ---------------- fixed workspace region (bytes) ----------------
#define WT_OFF   0ull                          // bf16 weightsT: 50,331,648
#define WC1T_OFF 50331648ull
#define WC2T_OFF 51380224ull
#define BC1_OFF  52428800ull
#define BC2_OFF  52432896ull
#define BQKV_OFF 52436992ull                   // fp32 NL*1536 = 49152
#define LOSS_OFF 52486144ull                   // fp32 2*22528 = 180224
#define FIXED_SZ 52666368ull
// per-chunk bytes: X bf16 (chb*135168) + Hb bf16 (chb*135168) + arena (chb*540672)
#define PER_CHB  811008ull

#define LAYER_WELEMS 3145728ull   // per-layer bf16 elems in WT arena

__device__ inline bf16x8 zero8() { u16x8 z = (u16x8)0; return *(bf16x8*)&z; }

// ---------------- GEMM: C[M,N] = A[M,K] @ Bt[N,K]^T (+bias +res +gelu) ----------------
// EPI bits: 1=bias, 2=residual(ResT, row-stride N), 4=gelu(sigmoid), 8=gathered-A
// (head GEMM: A row hr maps to X row (hr/44)*132 + segoff + hr%44).
// r8/r13-proven skeleton: 128x128, 3-buffer, 2-ahead, counted vmcnt(4), static phases.
// NO XCD swizzle: all working sets are L3-fit here (m160: swizzle costs ~2% when L3-fit).
#define AROW(hr_) ((EPI & 8) ? (size_t)(((unsigned)(hr_) / 44u) * 132u + (unsigned)segoff + ((unsigned)(hr_) % 44u)) : (size_t)(hr_))

#define STAGE(bufi, ktile) do { \
  _Pragma("unroll") \
  for (int i_ = 0; i_ < 2; ++i_) { \
    int off_ = wid * 2048 + i_ * 1024; \
    int myoff_ = off_ + lane * 16; \
    int row_ = myoff_ >> 6; \
    int colb_ = (myoff_ & 63) ^ ((row_ & 3) << 4); \
    const char* sa_ = (const char*)(A + AROW(arow + row_) * (size_t)KDIM + ((size_t)(ktile) << 5)) + colb_; \
    const char* sb_ = (const char*)(Bt + (brow + row_) * (size_t)KDIM + ((size_t)(ktile) << 5)) + colb_; \
    __builtin_amdgcn_global_load_lds((const __attribute__((address_space(1))) void*)sa_, \
        (__attribute__((address_space(3))) void*)((char*)&As[bufi][0] + off_), 16, 0, 0); \
    __builtin_amdgcn_global_load_lds((const __attribute__((address_space(1))) void*)sb_, \
        (__attribute__((address_space(3))) void*)((char*)&Bs[bufi][0] + off_), 16, 0, 0); \
  } \
} while (0)

// One K-phase with STATIC buffer index CURB; MORE is a compile-time literal.
#define PHASE(CURB, KTV, MORE) do { \
  bf16x8 af_[4], bfv_[4]; \
  _Pragma("unroll") \
  for (int mi_ = 0; mi_ < 4; ++mi_) \
    af_[mi_] = *(const bf16x8*)&As[CURB][(wr * 64 + mi_ * 16 + l15) * 32 + ((lk ^ swz) * 8)]; \
  _Pragma("unroll") \
  for (int ni_ = 0; ni_ < 4; ++ni_) \
    bfv_[ni_] = *(const bf16x8*)&Bs[CURB][(wc * 64 + ni_ * 16 + l15) * 32 + ((lk ^ swz) * 8)]; \
  if (MORE) STAGE(((CURB) + 2) % 3, (KTV) + 2); \
  _Pragma("unroll") \
  for (int mi_ = 0; mi_ < 4; ++mi_) \
    _Pragma("unroll") \
    for (int ni_ = 0; ni_ < 4; ++ni_) \
      acc[mi_][ni_] = __builtin_amdgcn_mfma_f32_16x16x32_bf16(af_[mi_], bfv_[ni_], acc[mi_][ni_], 0, 0, 0); \
  if (MORE) { asm volatile("s_waitcnt vmcnt(4)\n\ts_barrier" ::: "memory"); } \
  else      { asm volatile("s_waitcnt vmcnt(0)\n\ts_barrier" ::: "memory"); } \
} while (0)

template<int KDIM, int EPI, typename OutT, typename ResT>
__global__ __launch_bounds__(256) void gemm_bt(
    const __bf16* __restrict__ A, const __bf16* __restrict__ Bt,
    const float* __restrict__ bias, const ResT* __restrict__ resid,
    OutT* __restrict__ C, int M, int N, int segoff)
{
    __shared__ __bf16 As[3][128 * 32];
    __shared__ __bf16 Bs[3][128 * 32];
    const int tid = threadIdx.x, lane = tid & 63, wid = tid >> 6;
    const int l15 = lane & 15, lk = lane >> 4;
    const int wr = wid >> 1, wc = wid & 1;
    const int swz = l15 & 3;               // read-side chunk XOR (row&3 == l15&3)

    const int bn = blockIdx.x, bm = blockIdx.y;   // identity map (no XCD swizzle: L3-fit)

    f32x4 acc[4][4];
#pragma unroll
    for (int i = 0; i < 4; ++i)
#pragma unroll
        for (int j = 0; j < 4; ++j) acc[i][j] = (f32x4)0.f;

    const size_t arow = (size_t)bm * 128;
    const size_t brow = (size_t)bn * 128;
    constexpr int KT = KDIM >> 5;          // 16 / 24 / 64
    constexpr int M3 = (KT - 2) / 3;       // full staged triples

    STAGE(0, 0);
    STAGE(1, 1);
    asm volatile("s_waitcnt vmcnt(4)\n\ts_barrier" ::: "memory");

    for (int t3 = 0; t3 < M3; ++t3) {
        const int kt = t3 * 3;
        PHASE(0, kt, true);
        PHASE(1, kt + 1, true);
        PHASE(2, kt + 2, true);
    }
#pragma unroll
    for (int p = 3 * M3; p < KT; ++p) {
        const int pb = p % 3;              // folds to constant under full unroll
        if (pb == 0)      { if (p <= KT - 3) PHASE(0, p, true); else PHASE(0, p, false); }
        else if (pb == 1) { if (p <= KT - 3) PHASE(1, p, true); else PHASE(1, p, false); }
        else              { if (p <= KT - 3) PHASE(2, p, true); else PHASE(2, p, false); }
    }

#pragma unroll
    for (int mi = 0; mi < 4; ++mi) {
#pragma unroll
        for (int ni = 0; ni < 4; ++ni) {
            int n = bn * 128 + wc * 64 + ni * 16 + l15;
            float bv = (EPI & 1) ? bias[n] : 0.f;
#pragma unroll
            for (int r = 0; r < 4; ++r) {
                int m = bm * 128 + wr * 64 + mi * 16 + lk * 4 + r;
                float v = acc[mi][ni][r] + bv;
                if (EPI & 2) v += (float)resid[(size_t)m * N + n];
                if (EPI & 4) v = v / (1.f + __expf(-1.702f * v));   // x*sigmoid(1.702x)
                C[(size_t)m * N + n] = (OutT)v;
            }
        }
    }
}

// ---------------- fused attention: one block per (b_local,h), fused QKV input ----------------
#define KLS 68
#define VTS 164
__global__ __launch_bounds__(256) void attn_k(const __bf16* __restrict__ QKV,
                                              __bf16* __restrict__ Y)
{
    __shared__ __bf16 Kl[144 * KLS];
    __shared__ __bf16 Ql[144 * KLS];
    __shared__ __bf16 Vt[64 * VTS];      // [d][k]
    __shared__ __bf16 Pl[4][16 * VTS];   // per-wave [sq_local][k]
    const int tid = threadIdx.x, lane = tid & 63, wid = tid >> 6;
    const int l15 = lane & 15, lk = lane >> 4;
    const int bh = blockIdx.x;
    const int b = bh >> 3, h = bh & 7;
    const size_t base = ((size_t)b * S3) * QKVN + h * 64;   // Q at +0, K at +512, V at +1024
    const size_t ybase = ((size_t)b * S3) * CC + h * 64;

    // stage Q,K rows 0..131 (rows 132..143 stale: masked / store-guarded, NaN-safe)
    for (int i = tid; i < S3 * 8; i += 256) {
        int s = i >> 3, c = (i & 7) * 8;
        bf16x8 qv = *(const bf16x8*)(QKV + base + (size_t)s * QKVN + c);
        bf16x8 kv = *(const bf16x8*)(QKV + base + (size_t)s * QKVN + 512 + c);
        *(bf16x8*)&Ql[s * KLS + c] = qv;
        *(bf16x8*)&Kl[s * KLS + c] = kv;
    }
    // stage V transposed: paired rows, bf16x2 LDS writes
    for (int i = tid; i < (S3 / 2) * 8; i += 256) {
        int s2 = i >> 3, d0 = (i & 7) * 8;
        int s = s2 * 2;
        bf16x8 v0 = *(const bf16x8*)(QKV + base + (size_t)s * QKVN + 1024 + d0);
        bf16x8 v1 = *(const bf16x8*)(QKV + base + (size_t)(s + 1) * QKVN + 1024 + d0);
#pragma unroll
        for (int j = 0; j < 8; ++j) {
            bf16x2 pr; pr[0] = v0[j]; pr[1] = v1[j];
            *(bf16x2*)&Vt[(d0 + j) * VTS + s] = pr;
        }
    }
    // zero Vt pad cols s=132..163
    for (int i = tid; i < 64 * 32; i += 256) {
        int d = i >> 5, s = 132 + (i & 31);
        Vt[d * VTS + s] = (__bf16)0.f;
    }
    // zero P pad columns 144..163 (own wave region)
    for (int i = lane; i < 16 * 20; i += 64) {
        int r = i / 20, c2 = 144 + (i % 20);
        Pl[wid][r * VTS + c2] = (__bf16)0.f;
    }
    __syncthreads();

    for (int qb = wid; qb < 9; qb += 4) {
        int sq = qb * 16 + l15;
        int sqe = sq < S3 ? sq : (S3 - 1);
        // scores^T: St[sk][sq] via mfma(A=K, B=Q)
        bf16x8 qf0 = *(const bf16x8*)&Ql[(qb * 16 + l15) * KLS + 0 * 32 + lk * 8];
        bf16x8 qf1 = *(const bf16x8*)&Ql[(qb * 16 + l15) * KLS + 1 * 32 + lk * 8];
        f32x4 st[9];
#pragma unroll
        for (int kt = 0; kt < 9; ++kt) {
            f32x4 a = (f32x4)0.f;
            bf16x8 kf0 = *(const bf16x8*)&Kl[(kt * 16 + l15) * KLS + 0 * 32 + lk * 8];
            bf16x8 kf1 = *(const bf16x8*)&Kl[(kt * 16 + l15) * KLS + 1 * 32 + lk * 8];
            a = __builtin_amdgcn_mfma_f32_16x16x32_bf16(kf0, qf0, a, 0, 0, 0);
            a = __builtin_amdgcn_mfma_f32_16x16x32_bf16(kf1, qf1, a, 0, 0, 0);
            st[kt] = a;
        }
        int qm = sqe % TT;
        float mx = -1e30f;
#pragma unroll
        for (int kt = 0; kt < 9; ++kt)
#pragma unroll
            for (int r = 0; r < 4; ++r) {
                int sk = kt * 16 + lk * 4 + r;
                float sv = st[kt][r] * 0.125f;
                int kk = sk % TT;
                bool msk = (sk >= S3) || (kk > qm) || (qm >= WINW && kk <= qm - WINW);
                sv = msk ? -INFINITY : sv;
                st[kt][r] = sv;
                mx = fmaxf(mx, sv);
            }
        mx = fmaxf(mx, __shfl_xor(mx, 16));
        mx = fmaxf(mx, __shfl_xor(mx, 32));
        float sum = 0.f;
#pragma unroll
        for (int kt = 0; kt < 9; ++kt)
#pragma unroll
            for (int r = 0; r < 4; ++r) {
                float p = __expf(st[kt][r] - mx);   // arg <= 0, v_exp safe
                st[kt][r] = p;
                sum += p;
            }
        sum += __shfl_xor(sum, 16);
        sum += __shfl_xor(sum, 32);
        float inv = 1.f / sum;
#pragma unroll
        for (int kt = 0; kt < 9; ++kt) {
            bf16x4 pk;
#pragma unroll
            for (int r = 0; r < 4; ++r) pk[r] = (__bf16)(st[kt][r] * inv);
            *(bf16x4*)&Pl[wid][l15 * VTS + kt * 16 + lk * 4] = pk;
        }
        // PV: y[sq][d] via mfma(A=P, B=V)
#pragma unroll
        for (int dt = 0; dt < 4; ++dt) {
            f32x4 o = (f32x4)0.f;
#pragma unroll
            for (int ks = 0; ks < 5; ++ks) {
                bf16x8 pa = *(const bf16x8*)&Pl[wid][l15 * VTS + ks * 32 + lk * 8];
                bf16x8 vb = *(const bf16x8*)&Vt[(dt * 16 + l15) * VTS + ks * 32 + lk * 8];
                o = __builtin_amdgcn_mfma_f32_16x16x32_bf16(pa, vb, o, 0, 0, 0);
            }
            int d = dt * 16 + l15;
#pragma unroll
            for (int r = 0; r < 4; ++r) {
                int sqr = qb * 16 + lk * 4 + r;
                if (sqr < S3) Y[ybase + (size_t)sqr * CC + d] = (__bf16)o[r];
            }
        }
    }
}

// ---------------- layernorm over C (bf16 in), per segment params ----------------
__global__ __launch_bounds__(256) void ln3_k(const __bf16* __restrict__ X,
                                             const float* __restrict__ g,
                                             const float* __restrict__ be,
                                             __bf16* __restrict__ Hb)
{
    int row = blockIdx.x * 4 + (threadIdx.x >> 6);
    int lane = threadIdx.x & 63;
    int seg = (row % S3) / TT;
    bf16x8 xv = *(const bf16x8*)(X + (size_t)row * CC + lane * 8);
    float vv[8];
    float s = 0.f, ss = 0.f;
#pragma unroll
    for (int j = 0; j < 8; ++j) { vv[j] = (float)xv[j]; s += vv[j]; ss += vv[j] * vv[j]; }
#pragma unroll
    for (int o = 32; o; o >>= 1) { s += __shfl_xor(s, o); ss += __shfl_xor(ss, o); }
    float mu = s * (1.f / CC);
    float var = ss * (1.f / CC) - mu * mu;
    float rs = rsqrtf(var + 1e-5f);
    const float* gp = g + seg * CC + lane * 8;
    const float* bp = be + seg * CC + lane * 8;
    __bf16* op = Hb + (size_t)row * CC + lane * 8;
#pragma unroll
    for (int j = 0; j < 8; ++j) op[j] = (__bf16)((vv[j] - mu) * rs * gp[j] + bp[j]);
}

// ---------------- embedding gather (chunk, b0 = batch offset), bf16 out ----------------
__global__ __launch_bounds__(128) void embed_k(const int* __restrict__ label,
                                               const int* __restrict__ wav1,
                                               const int* __restrict__ wav2,
                                               const float* __restrict__ el,
                                               const float* __restrict__ e1,
                                               const float* __restrict__ e2,
                                               __bf16* __restrict__ X, int b0)
{
    int row = blockIdx.x;
    int b = b0 + row / S3, p = row % S3;
    int seg = p / TT, pos = p % TT;
    int idx; const float* src;
    if (seg == 0) { idx = label[b]; src = el; }
    else if (seg == 1) { idx = wav1[b * 45 + pos]; src = e1; }
    else { idx = wav2[b * 45 + pos]; src = e2; }
    float4 v = *((const float4*)(src + (size_t)idx * CC) + threadIdx.x);
    __bf16* dst = X + (size_t)row * CC + threadIdx.x * 4;
    dst[0] = (__bf16)v.x; dst[1] = (__bf16)v.y; dst[2] = (__bf16)v.z; dst[3] = (__bf16)v.w;
}

// ---------------- transpose + cast fp32(R,Cin) -> bf16(Np,R), zero pad ----------------
__global__ void transpose_cast(const float* __restrict__ in, __bf16* __restrict__ out,
                               int R, int Cin, int Np, long long inStride, long long outStride)
{
    __shared__ float t[32][33];
    in += (size_t)blockIdx.z * inStride;
    out += (size_t)blockIdx.z * outStride;
    int r0 = blockIdx.x * 32, c0 = blockIdx.y * 32;
    int tx = threadIdx.x, ty = threadIdx.y;
#pragma unroll
    for (int k2 = 0; k2 < 4; ++k2) {
        int r = r0 + ty + k2 * 8, c = c0 + tx;
        t[ty + k2 * 8][tx] = (r < R && c < Cin) ? in[(size_t)r * Cin + c] : 0.f;
    }
    __syncthreads();
#pragma unroll
    for (int k2 = 0; k2 < 4; ++k2) {
        int c = c0 + ty + k2 * 8, r = r0 + tx;
        if (c < Np && r < R) out[(size_t)c * R + r] = (__bf16)t[tx][ty + k2 * 8];
    }
}

// ---------------- flat cast fp32 -> bf16 ----------------
__global__ void cast_k(const float* __restrict__ in, __bf16* __restrict__ out, int n)
{
    int i = blockIdx.x * 256 + threadIdx.x;
    if (i < n) out[i] = (__bf16)in[i];
}

// ---------------- combined qkv bias [NL][1536] ----------------
__global__ void build_bqkv(const float* __restrict__ bq, const float* __restrict__ bk,
                           const float* __restrict__ bv, float* __restrict__ out)
{
    int i = blockIdx.x * 256 + threadIdx.x;
    if (i >= NL * QKVN) return;
    int l = i / QKVN, c = i % QKVN;
    float v = (c < 512) ? bq[l * 512 + c] : (c < 1024 ? bk[l * 512 + c - 512] : bv[l * 512 + c - 1024]);
    out[i] = v;
}

// ---------------- combined head bias: bc[v] = b2[v] + sum_o b1[o]*W2[o,v] ----------------
__global__ __launch_bounds__(256) void combo_bias(const float* __restrict__ b1,
                                                  const float* __restrict__ W2,
                                                  const float* __restrict__ b2,
                                                  float* __restrict__ out)
{
    int v = blockIdx.x;
    if (v >= VP) return;
    float s = 0.f;
    if (v < NV) {
        for (int o = threadIdx.x; o < OH; o += 256) s += b1[o] * W2[o * NV + v];
    }
#pragma unroll
    for (int o = 32; o; o >>= 1) s += __shfl_xor(s, o);
    __shared__ float w4[4];
    if ((threadIdx.x & 63) == 0) w4[threadIdx.x >> 6] = s;
    __syncthreads();
    if (threadIdx.x == 0) out[v] = (v < NV ? b2[v] : 0.f) + w4[0] + w4[1] + w4[2] + w4[3];
}

// ---------------- per-row CE loss over bf16 logits (wav pre-offset by b0*45) ----------------
__global__ __launch_bounds__(256) void ce_k(const __bf16* __restrict__ logits,
                                            const int* __restrict__ wav,
                                            float* __restrict__ loss)
{
    int row = blockIdx.x * 4 + (threadIdx.x >> 6);
    int lane = threadIdx.x & 63;
    const __bf16* lg = logits + (size_t)row * VP;
    int b = row / TT, s2 = row % TT;
    int tgt = wav[b * 45 + s2 + 1];
    float m = -1e30f;
    for (int i2 = lane; i2 < NV / 2; i2 += 64) {
        bf16x2 pr = *(const bf16x2*)(lg + 2 * i2);
        m = fmaxf(m, fmaxf((float)pr[0], (float)pr[1]));
    }
#pragma unroll
    for (int o = 32; o; o >>= 1) m = fmaxf(m, __shfl_xor(m, o));
    float sum = 0.f;
    for (int i2 = lane; i2 < NV / 2; i2 += 64) {
        bf16x2 pr = *(const bf16x2*)(lg + 2 * i2);
        sum += __expf((float)pr[0] - m) + __expf((float)pr[1] - m);
    }
#pragma unroll
    for (int o = 32; o; o >>= 1) sum += __shfl_xor(sum, o);
    if (lane == 0) loss[row] = m + logf(sum) - (float)lg[tgt];
}

// ---------------- final deterministic sum ----------------
__global__ __launch_bounds__(256) void ce_sum(const float* __restrict__ loss, float* __restrict__ out)
{
    float s = 0.f;
    for (int i = threadIdx.x; i < 2 * HROWS; i += 256) s += loss[i];
#pragma unroll
    for (int o = 32; o; o >>= 1) s += __shfl_xor(s, o);
    __shared__ float w4[4];
    if ((threadIdx.x & 63) == 0) w4[threadIdx.x >> 6] = s;
    __syncthreads();
    if (threadIdx.x == 0) out[0] = (w4[0] + w4[1] + w4[2] + w4[3]) * (1.f / HROWS);
}

extern "C" void kernel_launch(void* const* d_in, const int* in_sizes, int n_in,
                              void* d_out, int out_size, void* d_ws, size_t ws_size,
                              hipStream_t stream)
{
    // chunk-size autoselect (deterministic: ws_size is fixed across calls)
    int chb;
    if      (ws_size >= FIXED_SZ + 512ull * PER_CHB) chb = 512;
    else if (ws_size >= FIXED_SZ + 256ull * PER_CHB) chb = 256;
    else if (ws_size >= FIXED_SZ + 128ull * PER_CHB) chb = 128;
    else return;
    const int nch = NB / chb;
    const int crows = chb * S3;
    const int chr = chb * TT;

    const int*   label = (const int*)d_in[0];
    const int*   wav1  = (const int*)d_in[1];
    const int*   wav2  = (const int*)d_in[2];
    const float* el    = (const float*)d_in[3];
    const float* e1    = (const float*)d_in[4];
    const float* e2    = (const float*)d_in[5];
    const float* ln1g  = (const float*)d_in[6];
    const float* ln1b  = (const float*)d_in[7];
    const float* ln2g  = (const float*)d_in[8];
    const float* ln2b  = (const float*)d_in[9];
    const float* Wq    = (const float*)d_in[10];
    const float* bq    = (const float*)d_in[11];
    const float* Wk    = (const float*)d_in[12];
    const float* bk    = (const float*)d_in[13];
    const float* Wv    = (const float*)d_in[14];
    const float* bv    = (const float*)d_in[15];
    const float* Wp    = (const float*)d_in[16];
    const float* bp    = (const float*)d_in[17];
    const float* W1    = (const float*)d_in[18];
    const float* b1    = (const float*)d_in[19];
    const float* W2    = (const float*)d_in[20];
    const float* b2    = (const float*)d_in[21];
    const float* o1W1  = (const float*)d_in[22];
    const float* o1b1  = (const float*)d_in[23];
    const float* o1W2  = (const float*)d_in[24];
    const float* o1b2  = (const float*)d_in[25];
    const float* o2W1  = (const float*)d_in[26];
    const float* o2b1  = (const float*)d_in[27];
    const float* o2W2  = (const float*)d_in[28];
    const float* o2b2  = (const float*)d_in[29];

    char* ws = (char*)d_ws;
    __bf16* WT    = (__bf16*)(ws + WT_OFF);
    __bf16* Wc1T  = (__bf16*)(ws + WC1T_OFF);
    __bf16* Wc2T  = (__bf16*)(ws + WC2T_OFF);
    float*  bc1   = (float*)(ws + BC1_OFF);
    float*  bc2   = (float*)(ws + BC2_OFF);
    float*  bqkv  = (float*)(ws + BQKV_OFF);
    float*  lossb = (float*)(ws + LOSS_OFF);
    __bf16* X     = (__bf16*)(ws + FIXED_SZ);
    __bf16* Hb    = (__bf16*)(ws + FIXED_SZ + (size_t)chb * 135168ull);
    char*   AR    = ws + FIXED_SZ + (size_t)chb * 270336ull;
    // prep temps alias the chunk arena (used only before the chunk loop)
    __bf16* o1W2T = (__bf16*)(AR + 0);
    __bf16* o2W2T = (__bf16*)(AR + 1572864);
    __bf16* o1W1b = (__bf16*)(AR + 3145728);
    __bf16* o2W1b = (__bf16*)(AR + 3932160);
    // per-chunk views
    __bf16* qkvb    = (__bf16*)AR;            // [crows][1536]
    __bf16* yb_     = Hb;                     // y aliases Hb (free after qkv gemm)
    __bf16* hidden  = (__bf16*)AR;
    __bf16* logitsB = (__bf16*)AR;            // bf16 logits [chr][VP]
    float*  outF    = (float*)d_out;

    dim3 tb(32, 8);
    // per-layer weight transposes (z = layer); q,k,v contiguous -> fused [1536,512]
    transpose_cast<<<dim3(16, 16, NL), tb, 0, stream>>>(Wq, WT + 0,       CC, CC, CC, (long long)CC * CC, (long long)LAYER_WELEMS);
    transpose_cast<<<dim3(16, 16, NL), tb, 0, stream>>>(Wk, WT + 262144,  CC, CC, CC, (long long)CC * CC, (long long)LAYER_WELEMS);
    transpose_cast<<<dim3(16, 16, NL), tb, 0, stream>>>(Wv, WT + 524288,  CC, CC, CC, (long long)CC * CC, (long long)LAYER_WELEMS);
    transpose_cast<<<dim3(16, 16, NL), tb, 0, stream>>>(Wp, WT + 786432,  CC, CC, CC, (long long)CC * CC, (long long)LAYER_WELEMS);
    transpose_cast<<<dim3(16, 64, NL), tb, 0, stream>>>(W1, WT + 1048576, CC, HID, HID, (long long)CC * HID, (long long)LAYER_WELEMS);
    transpose_cast<<<dim3(64, 16, NL), tb, 0, stream>>>(W2, WT + 2097152, HID, CC, CC, (long long)HID * CC, (long long)LAYER_WELEMS);
    // head weight prep
    transpose_cast<<<dim3(24, 32, 1), tb, 0, stream>>>(o1W2, o1W2T, OH, NV, VP, 0, 0);
    transpose_cast<<<dim3(24, 32, 1), tb, 0, stream>>>(o2W2, o2W2T, OH, NV, VP, 0, 0);
    cast_k<<<(CC * OH + 255) / 256, 256, 0, stream>>>(o1W1, o1W1b, CC * OH);
    cast_k<<<(CC * OH + 255) / 256, 256, 0, stream>>>(o2W1, o2W1b, CC * OH);
    // WcT[VP,CC] = collapsed head weight (K=768)
    gemm_bt<OH, 0, __bf16, float><<<dim3(4, 8), 256, 0, stream>>>(o1W2T, o1W1b, nullptr, nullptr, Wc1T, VP, CC, 0);
    gemm_bt<OH, 0, __bf16, float><<<dim3(4, 8), 256, 0, stream>>>(o2W2T, o2W1b, nullptr, nullptr, Wc2T, VP, CC, 0);
    combo_bias<<<VP, 256, 0, stream>>>(o1b1, o1W2, o1b2, bc1);
    combo_bias<<<VP, 256, 0, stream>>>(o2b1, o2W2, o2b2, bc2);
    build_bqkv<<<(NL * QKVN + 255) / 256, 256, 0, stream>>>(bq, bk, bv, bqkv);

    for (int c = 0; c < nch; ++c) {
        int b0 = c * chb;
        embed_k<<<crows, 128, 0, stream>>>(label, wav1, wav2, el, e1, e2, X, b0);

        for (int l = 0; l < NL; ++l) {
            const __bf16* WqkvT = WT + (size_t)l * LAYER_WELEMS;          // [1536,512]
            const __bf16* WpT   = WT + (size_t)l * LAYER_WELEMS + 786432;
            const __bf16* W1T   = WT + (size_t)l * LAYER_WELEMS + 1048576;
            const __bf16* W2T   = WT + (size_t)l * LAYER_WELEMS + 2097152;

            ln3_k<<<crows / 4, 256, 0, stream>>>(X, ln1g + l * 3 * CC, ln1b + l * 3 * CC, Hb);
            gemm_bt<CC, 1, __bf16, float><<<dim3(QKVN / 128, crows / 128), 256, 0, stream>>>(Hb, WqkvT, bqkv + l * QKVN, nullptr, qkvb, crows, QKVN, 0);
            attn_k<<<chb * NH, 256, 0, stream>>>(qkvb, yb_);
            gemm_bt<CC, 3, __bf16, __bf16><<<dim3(4, crows / 128), 256, 0, stream>>>(yb_, WpT, bp + l * CC, X, X, crows, CC, 0);
            ln3_k<<<crows / 4, 256, 0, stream>>>(X, ln2g + l * 3 * CC, ln2b + l * 3 * CC, Hb);
            gemm_bt<CC, 5, __bf16, float><<<dim3(16, crows / 128), 256, 0, stream>>>(Hb, W1T, b1 + l * HID, nullptr, hidden, crows, HID, 0);
            gemm_bt<HID, 3, __bf16, __bf16><<<dim3(4, crows / 128), 256, 0, stream>>>(hidden, W2T, b2 + l * CC, X, X, crows, CC, 0);
        }

        // head 1: gathered-A GEMM straight from X (seg offset 44), bf16 logits
        gemm_bt<CC, 9, __bf16, float><<<dim3(VP / 128, chr / 128), 256, 0, stream>>>(X, Wc1T, bc1, nullptr, logitsB, chr, VP, TT);
        ce_k<<<chr / 4, 256, 0, stream>>>(logitsB, wav1 + b0 * 45, lossb + c * chr);
        // head 2 (seg offset 88)
        gemm_bt<CC, 9, __bf16, float><<<dim3(VP / 128, chr / 128), 256, 0, stream>>>(X, Wc2T, bc2, nullptr, logitsB, chr, VP, 2 * TT);
        ce_k<<<chr / 4, 256, 0, stream>>>(logitsB, wav2 + b0 * 45, lossb + HROWS + c * chr);
    }

    ce_sum<<<1, 256, 0, stream>>>(lossb, outF);
}

// Round 18
// 7295.802 us; speedup vs baseline: 1.0750x; 1.0750x over previous
//
#include <hip/hip_runtime.h>

typedef __attribute__((ext_vector_type(4))) float f32x4;
typedef __attribute__((ext_vector_type(8))) __bf16 bf16x8;
typedef __attribute__((ext_vector_type(4))) __bf16 bf16x4;
typedef __attribute__((ext_vector_type(2))) __bf16 bf16x2;
typedef __attribute__((ext_vector_type(8))) unsigned short u16x8;

#define NB 512      // batch
#define TT 44       // t
#define S3 132      // 3*t
#define CC 512      // C
#define NH 8        // heads
#define NL 8        // layers
#define NV 1000     // vocab
#define VP 1024     // padded vocab
#define HID 2048
#define OH 768
#define WINW 30
#define QKVN 1536   // fused q,k,v output width

#define HROWS (NB*TT)         // 22528 total head rows

// ---------------- fixed workspace region (bytes) ----------------
#define WT_OFF   0ull                          // bf16 weightsT: 50,331,648
#define WC1T_OFF 50331648ull
#define WC2T_OFF 51380224ull
#define BC1_OFF  52428800ull
#define BC2_OFF  52432896ull
#define BQKV_OFF 52436992ull                   // fp32 NL*1536 = 49152
#define LOSS_OFF 52486144ull                   // fp32 2*22528 = 180224
#define FIXED_SZ 52666368ull
// per-chunk bytes: X bf16 (chb*135168) + Hb bf16 (chb*135168) + arena (chb*540672)
#define PER_CHB  811008ull

#define LAYER_WELEMS 3145728ull   // per-layer bf16 elems in WT arena

__device__ inline bf16x8 zero8() { u16x8 z = (u16x8)0; return *(bf16x8*)&z; }

// ---------------- GEMM: C[M,N] = A[M,K] @ Bt[N,K]^T (+bias +res +gelu) ----------------
// EPI bits: 1=bias, 2=residual(ResT, row-stride N), 4=gelu(sigmoid), 8=gathered-A
// (head GEMM: A row hr maps to X row (hr/44)*132 + segoff + hr%44).
// r8/r13-proven skeleton: 128x128, 3-buffer, 2-ahead, counted vmcnt(4), static phases.
// XCD swizzle REQUIRED here (r17 A/B: removing it doubled FETCH 61->143MB, +530us):
// it keeps blocks sharing an A-panel on one XCD -> L2-local panel reuse.
#define AROW(hr_) ((EPI & 8) ? (size_t)(((unsigned)(hr_) / 44u) * 132u + (unsigned)segoff + ((unsigned)(hr_) % 44u)) : (size_t)(hr_))

#define STAGE(bufi, ktile) do { \
  _Pragma("unroll") \
  for (int i_ = 0; i_ < 2; ++i_) { \
    int off_ = wid * 2048 + i_ * 1024; \
    int myoff_ = off_ + lane * 16; \
    int row_ = myoff_ >> 6; \
    int colb_ = (myoff_ & 63) ^ ((row_ & 3) << 4); \
    const char* sa_ = (const char*)(A + AROW(arow + row_) * (size_t)KDIM + ((size_t)(ktile) << 5)) + colb_; \
    const char* sb_ = (const char*)(Bt + (brow + row_) * (size_t)KDIM + ((size_t)(ktile) << 5)) + colb_; \
    __builtin_amdgcn_global_load_lds((const __attribute__((address_space(1))) void*)sa_, \
        (__attribute__((address_space(3))) void*)((char*)&As[bufi][0] + off_), 16, 0, 0); \
    __builtin_amdgcn_global_load_lds((const __attribute__((address_space(1))) void*)sb_, \
        (__attribute__((address_space(3))) void*)((char*)&Bs[bufi][0] + off_), 16, 0, 0); \
  } \
} while (0)

// One K-phase with STATIC buffer index CURB; MORE is a compile-time literal.
#define PHASE(CURB, KTV, MORE) do { \
  bf16x8 af_[4], bfv_[4]; \
  _Pragma("unroll") \
  for (int mi_ = 0; mi_ < 4; ++mi_) \
    af_[mi_] = *(const bf16x8*)&As[CURB][(wr * 64 + mi_ * 16 + l15) * 32 + ((lk ^ swz) * 8)]; \
  _Pragma("unroll") \
  for (int ni_ = 0; ni_ < 4; ++ni_) \
    bfv_[ni_] = *(const bf16x8*)&Bs[CURB][(wc * 64 + ni_ * 16 + l15) * 32 + ((lk ^ swz) * 8)]; \
  if (MORE) STAGE(((CURB) + 2) % 3, (KTV) + 2); \
  _Pragma("unroll") \
  for (int mi_ = 0; mi_ < 4; ++mi_) \
    _Pragma("unroll") \
    for (int ni_ = 0; ni_ < 4; ++ni_) \
      acc[mi_][ni_] = __builtin_amdgcn_mfma_f32_16x16x32_bf16(af_[mi_], bfv_[ni_], acc[mi_][ni_], 0, 0, 0); \
  if (MORE) { asm volatile("s_waitcnt vmcnt(4)\n\ts_barrier" ::: "memory"); } \
  else      { asm volatile("s_waitcnt vmcnt(0)\n\ts_barrier" ::: "memory"); } \
} while (0)

template<int KDIM, int EPI, typename OutT, typename ResT>
__global__ __launch_bounds__(256) void gemm_bt(
    const __bf16* __restrict__ A, const __bf16* __restrict__ Bt,
    const float* __restrict__ bias, const ResT* __restrict__ resid,
    OutT* __restrict__ C, int M, int N, int segoff)
{
    __shared__ __bf16 As[3][128 * 32];
    __shared__ __bf16 Bs[3][128 * 32];
    const int tid = threadIdx.x, lane = tid & 63, wid = tid >> 6;
    const int l15 = lane & 15, lk = lane >> 4;
    const int wr = wid >> 1, wc = wid & 1;
    const int swz = l15 & 3;               // read-side chunk XOR (row&3 == l15&3)

    // bijective XCD-aware block swizzle (m204)
    const int nwg = gridDim.x * gridDim.y;
    const int orig = blockIdx.y * gridDim.x + blockIdx.x;
    const int qq = nwg >> 3, rr = nwg & 7;
    const int xcd = orig & 7, loc = orig >> 3;
    const int wg = (xcd < rr ? xcd * (qq + 1) : rr * (qq + 1) + (xcd - rr) * qq) + loc;
    const int bn = wg % gridDim.x, bm = wg / gridDim.x;

    f32x4 acc[4][4];
#pragma unroll
    for (int i = 0; i < 4; ++i)
#pragma unroll
        for (int j = 0; j < 4; ++j) acc[i][j] = (f32x4)0.f;

    const size_t arow = (size_t)bm * 128;
    const size_t brow = (size_t)bn * 128;
    constexpr int KT = KDIM >> 5;          // 16 / 24 / 64
    constexpr int M3 = (KT - 2) / 3;       // full staged triples

    STAGE(0, 0);
    STAGE(1, 1);
    asm volatile("s_waitcnt vmcnt(4)\n\ts_barrier" ::: "memory");

    for (int t3 = 0; t3 < M3; ++t3) {
        const int kt = t3 * 3;
        PHASE(0, kt, true);
        PHASE(1, kt + 1, true);
        PHASE(2, kt + 2, true);
    }
#pragma unroll
    for (int p = 3 * M3; p < KT; ++p) {
        const int pb = p % 3;              // folds to constant under full unroll
        if (pb == 0)      { if (p <= KT - 3) PHASE(0, p, true); else PHASE(0, p, false); }
        else if (pb == 1) { if (p <= KT - 3) PHASE(1, p, true); else PHASE(1, p, false); }
        else              { if (p <= KT - 3) PHASE(2, p, true); else PHASE(2, p, false); }
    }

#pragma unroll
    for (int mi = 0; mi < 4; ++mi) {
#pragma unroll
        for (int ni = 0; ni < 4; ++ni) {
            int n = bn * 128 + wc * 64 + ni * 16 + l15;
            float bv = (EPI & 1) ? bias[n] : 0.f;
#pragma unroll
            for (int r = 0; r < 4; ++r) {
                int m = bm * 128 + wr * 64 + mi * 16 + lk * 4 + r;
                float v = acc[mi][ni][r] + bv;
                if (EPI & 2) v += (float)resid[(size_t)m * N + n];
                if (EPI & 4) v = v / (1.f + __expf(-1.702f * v));   // x*sigmoid(1.702x)
                C[(size_t)m * N + n] = (OutT)v;
            }
        }
    }
}

// ---------------- fused attention: one block per (b_local,h), fused QKV input ----------------
#define KLS 68
#define VTS 164
__global__ __launch_bounds__(256) void attn_k(const __bf16* __restrict__ QKV,
                                              __bf16* __restrict__ Y)
{
    __shared__ __bf16 Kl[144 * KLS];
    __shared__ __bf16 Ql[144 * KLS];
    __shared__ __bf16 Vt[64 * VTS];      // [d][k]
    __shared__ __bf16 Pl[4][16 * VTS];   // per-wave [sq_local][k]
    const int tid = threadIdx.x, lane = tid & 63, wid = tid >> 6;
    const int l15 = lane & 15, lk = lane >> 4;
    const int bh = blockIdx.x;
    const int b = bh >> 3, h = bh & 7;
    const size_t base = ((size_t)b * S3) * QKVN + h * 64;   // Q at +0, K at +512, V at +1024
    const size_t ybase = ((size_t)b * S3) * CC + h * 64;

    // stage Q,K rows 0..131 (rows 132..143 stale: masked / store-guarded, NaN-safe)
    for (int i = tid; i < S3 * 8; i += 256) {
        int s = i >> 3, c = (i & 7) * 8;
        bf16x8 qv = *(const bf16x8*)(QKV + base + (size_t)s * QKVN + c);
        bf16x8 kv = *(const bf16x8*)(QKV + base + (size_t)s * QKVN + 512 + c);
        *(bf16x8*)&Ql[s * KLS + c] = qv;
        *(bf16x8*)&Kl[s * KLS + c] = kv;
    }
    // stage V transposed: paired rows, bf16x2 LDS writes
    for (int i = tid; i < (S3 / 2) * 8; i += 256) {
        int s2 = i >> 3, d0 = (i & 7) * 8;
        int s = s2 * 2;
        bf16x8 v0 = *(const bf16x8*)(QKV + base + (size_t)s * QKVN + 1024 + d0);
        bf16x8 v1 = *(const bf16x8*)(QKV + base + (size_t)(s + 1) * QKVN + 1024 + d0);
#pragma unroll
        for (int j = 0; j < 8; ++j) {
            bf16x2 pr; pr[0] = v0[j]; pr[1] = v1[j];
            *(bf16x2*)&Vt[(d0 + j) * VTS + s] = pr;
        }
    }
    // zero Vt pad cols s=132..163
    for (int i = tid; i < 64 * 32; i += 256) {
        int d = i >> 5, s = 132 + (i & 31);
        Vt[d * VTS + s] = (__bf16)0.f;
    }
    // zero P pad columns 144..163 (own wave region)
    for (int i = lane; i < 16 * 20; i += 64) {
        int r = i / 20, c2 = 144 + (i % 20);
        Pl[wid][r * VTS + c2] = (__bf16)0.f;
    }
    __syncthreads();

    for (int qb = wid; qb < 9; qb += 4) {
        int sq = qb * 16 + l15;
        int sqe = sq < S3 ? sq : (S3 - 1);
        // scores^T: St[sk][sq] via mfma(A=K, B=Q)
        bf16x8 qf0 = *(const bf16x8*)&Ql[(qb * 16 + l15) * KLS + 0 * 32 + lk * 8];
        bf16x8 qf1 = *(const bf16x8*)&Ql[(qb * 16 + l15) * KLS + 1 * 32 + lk * 8];
        f32x4 st[9];
#pragma unroll
        for (int kt = 0; kt < 9; ++kt) {
            f32x4 a = (f32x4)0.f;
            bf16x8 kf0 = *(const bf16x8*)&Kl[(kt * 16 + l15) * KLS + 0 * 32 + lk * 8];
            bf16x8 kf1 = *(const bf16x8*)&Kl[(kt * 16 + l15) * KLS + 1 * 32 + lk * 8];
            a = __builtin_amdgcn_mfma_f32_16x16x32_bf16(kf0, qf0, a, 0, 0, 0);
            a = __builtin_amdgcn_mfma_f32_16x16x32_bf16(kf1, qf1, a, 0, 0, 0);
            st[kt] = a;
        }
        int qm = sqe % TT;
        float mx = -1e30f;
#pragma unroll
        for (int kt = 0; kt < 9; ++kt)
#pragma unroll
            for (int r = 0; r < 4; ++r) {
                int sk = kt * 16 + lk * 4 + r;
                float sv = st[kt][r] * 0.125f;
                int kk = sk % TT;
                bool msk = (sk >= S3) || (kk > qm) || (qm >= WINW && kk <= qm - WINW);
                sv = msk ? -INFINITY : sv;
                st[kt][r] = sv;
                mx = fmaxf(mx, sv);
            }
        mx = fmaxf(mx, __shfl_xor(mx, 16));
        mx = fmaxf(mx, __shfl_xor(mx, 32));
        float sum = 0.f;
#pragma unroll
        for (int kt = 0; kt < 9; ++kt)
#pragma unroll
            for (int r = 0; r < 4; ++r) {
                float p = __expf(st[kt][r] - mx);   // arg <= 0, v_exp safe
                st[kt][r] = p;
                sum += p;
            }
        sum += __shfl_xor(sum, 16);
        sum += __shfl_xor(sum, 32);
        float inv = 1.f / sum;
#pragma unroll
        for (int kt = 0; kt < 9; ++kt) {
            bf16x4 pk;
#pragma unroll
            for (int r = 0; r < 4; ++r) pk[r] = (__bf16)(st[kt][r] * inv);
            *(bf16x4*)&Pl[wid][l15 * VTS + kt * 16 + lk * 4] = pk;
        }
        // PV: y[sq][d] via mfma(A=P, B=V)
#pragma unroll
        for (int dt = 0; dt < 4; ++dt) {
            f32x4 o = (f32x4)0.f;
#pragma unroll
            for (int ks = 0; ks < 5; ++ks) {
                bf16x8 pa = *(const bf16x8*)&Pl[wid][l15 * VTS + ks * 32 + lk * 8];
                bf16x8 vb = *(const bf16x8*)&Vt[(dt * 16 + l15) * VTS + ks * 32 + lk * 8];
                o = __builtin_amdgcn_mfma_f32_16x16x32_bf16(pa, vb, o, 0, 0, 0);
            }
            int d = dt * 16 + l15;
#pragma unroll
            for (int r = 0; r < 4; ++r) {
                int sqr = qb * 16 + lk * 4 + r;
                if (sqr < S3) Y[ybase + (size_t)sqr * CC + d] = (__bf16)o[r];
            }
        }
    }
}

// ---------------- layernorm over C (bf16 in), per segment params ----------------
__global__ __launch_bounds__(256) void ln3_k(const __bf16* __restrict__ X,
                                             const float* __restrict__ g,
                                             const float* __restrict__ be,
                                             __bf16* __restrict__ Hb)
{
    int row = blockIdx.x * 4 + (threadIdx.x >> 6);
    int lane = threadIdx.x & 63;
    int seg = (row % S3) / TT;
    bf16x8 xv = *(const bf16x8*)(X + (size_t)row * CC + lane * 8);
    float vv[8];
    float s = 0.f, ss = 0.f;
#pragma unroll
    for (int j = 0; j < 8; ++j) { vv[j] = (float)xv[j]; s += vv[j]; ss += vv[j] * vv[j]; }
#pragma unroll
    for (int o = 32; o; o >>= 1) { s += __shfl_xor(s, o); ss += __shfl_xor(ss, o); }
    float mu = s * (1.f / CC);
    float var = ss * (1.f / CC) - mu * mu;
    float rs = rsqrtf(var + 1e-5f);
    const float* gp = g + seg * CC + lane * 8;
    const float* bp = be + seg * CC + lane * 8;
    __bf16* op = Hb + (size_t)row * CC + lane * 8;
#pragma unroll
    for (int j = 0; j < 8; ++j) op[j] = (__bf16)((vv[j] - mu) * rs * gp[j] + bp[j]);
}

// ---------------- embedding gather (chunk, b0 = batch offset), bf16 out ----------------
__global__ __launch_bounds__(128) void embed_k(const int* __restrict__ label,
                                               const int* __restrict__ wav1,
                                               const int* __restrict__ wav2,
                                               const float* __restrict__ el,
                                               const float* __restrict__ e1,
                                               const float* __restrict__ e2,
                                               __bf16* __restrict__ X, int b0)
{
    int row = blockIdx.x;
    int b = b0 + row / S3, p = row % S3;
    int seg = p / TT, pos = p % TT;
    int idx; const float* src;
    if (seg == 0) { idx = label[b]; src = el; }
    else if (seg == 1) { idx = wav1[b * 45 + pos]; src = e1; }
    else { idx = wav2[b * 45 + pos]; src = e2; }
    float4 v = *((const float4*)(src + (size_t)idx * CC) + threadIdx.x);
    __bf16* dst = X + (size_t)row * CC + threadIdx.x * 4;
    dst[0] = (__bf16)v.x; dst[1] = (__bf16)v.y; dst[2] = (__bf16)v.z; dst[3] = (__bf16)v.w;
}

// ---------------- transpose + cast fp32(R,Cin) -> bf16(Np,R), zero pad ----------------
__global__ void transpose_cast(const float* __restrict__ in, __bf16* __restrict__ out,
                               int R, int Cin, int Np, long long inStride, long long outStride)
{
    __shared__ float t[32][33];
    in += (size_t)blockIdx.z * inStride;
    out += (size_t)blockIdx.z * outStride;
    int r0 = blockIdx.x * 32, c0 = blockIdx.y * 32;
    int tx = threadIdx.x, ty = threadIdx.y;
#pragma unroll
    for (int k2 = 0; k2 < 4; ++k2) {
        int r = r0 + ty + k2 * 8, c = c0 + tx;
        t[ty + k2 * 8][tx] = (r < R && c < Cin) ? in[(size_t)r * Cin + c] : 0.f;
    }
    __syncthreads();
#pragma unroll
    for (int k2 = 0; k2 < 4; ++k2) {
        int c = c0 + ty + k2 * 8, r = r0 + tx;
        if (c < Np && r < R) out[(size_t)c * R + r] = (__bf16)t[tx][ty + k2 * 8];
    }
}

// ---------------- flat cast fp32 -> bf16 ----------------
__global__ void cast_k(const float* __restrict__ in, __bf16* __restrict__ out, int n)
{
    int i = blockIdx.x * 256 + threadIdx.x;
    if (i < n) out[i] = (__bf16)in[i];
}

// ---------------- combined qkv bias [NL][1536] ----------------
__global__ void build_bqkv(const float* __restrict__ bq, const float* __restrict__ bk,
                           const float* __restrict__ bv, float* __restrict__ out)
{
    int i = blockIdx.x * 256 + threadIdx.x;
    if (i >= NL * QKVN) return;
    int l = i / QKVN, c = i % QKVN;
    float v = (c < 512) ? bq[l * 512 + c] : (c < 1024 ? bk[l * 512 + c - 512] : bv[l * 512 + c - 1024]);
    out[i] = v;
}

// ---------------- combined head bias: bc[v] = b2[v] + sum_o b1[o]*W2[o,v] ----------------
__global__ __launch_bounds__(256) void combo_bias(const float* __restrict__ b1,
                                                  const float* __restrict__ W2,
                                                  const float* __restrict__ b2,
                                                  float* __restrict__ out)
{
    int v = blockIdx.x;
    if (v >= VP) return;
    float s = 0.f;
    if (v < NV) {
        for (int o = threadIdx.x; o < OH; o += 256) s += b1[o] * W2[o * NV + v];
    }
#pragma unroll
    for (int o = 32; o; o >>= 1) s += __shfl_xor(s, o);
    __shared__ float w4[4];
    if ((threadIdx.x & 63) == 0) w4[threadIdx.x >> 6] = s;
    __syncthreads();
    if (threadIdx.x == 0) out[v] = (v < NV ? b2[v] : 0.f) + w4[0] + w4[1] + w4[2] + w4[3];
}

// ---------------- per-row CE loss over bf16 logits (wav pre-offset by b0*45) ----------------
__global__ __launch_bounds__(256) void ce_k(const __bf16* __restrict__ logits,
                                            const int* __restrict__ wav,
                                            float* __restrict__ loss)
{
    int row = blockIdx.x * 4 + (threadIdx.x >> 6);
    int lane = threadIdx.x & 63;
    const __bf16* lg = logits + (size_t)row * VP;
    int b = row / TT, s2 = row % TT;
    int tgt = wav[b * 45 + s2 + 1];
    float m = -1e30f;
    for (int i2 = lane; i2 < NV / 2; i2 += 64) {
        bf16x2 pr = *(const bf16x2*)(lg + 2 * i2);
        m = fmaxf(m, fmaxf((float)pr[0], (float)pr[1]));
    }
#pragma unroll
    for (int o = 32; o; o >>= 1) m = fmaxf(m, __shfl_xor(m, o));
    float sum = 0.f;
    for (int i2 = lane; i2 < NV / 2; i2 += 64) {
        bf16x2 pr = *(const bf16x2*)(lg + 2 * i2);
        sum += __expf((float)pr[0] - m) + __expf((float)pr[1] - m);
    }
#pragma unroll
    for (int o = 32; o; o >>= 1) sum += __shfl_xor(sum, o);
    if (lane == 0) loss[row] = m + logf(sum) - (float)lg[tgt];
}

// ---------------- final deterministic sum ----------------
__global__ __launch_bounds__(256) void ce_sum(const float* __restrict__ loss, float* __restrict__ out)
{
    float s = 0.f;
    for (int i = threadIdx.x; i < 2 * HROWS; i += 256) s += loss[i];
#pragma unroll
    for (int o = 32; o; o >>= 1) s += __shfl_xor(s, o);
    __shared__ float w4[4];
    if ((threadIdx.x & 63) == 0) w4[threadIdx.x >> 6] = s;
    __syncthreads();
    if (threadIdx.x == 0) out[0] = (w4[0] + w4[1] + w4[2] + w4[3]) * (1.f / HROWS);
}

extern "C" void kernel_launch(void* const* d_in, const int* in_sizes, int n_in,
                              void* d_out, int out_size, void* d_ws, size_t ws_size,
                              hipStream_t stream)
{
    // chunk-size autoselect (deterministic: ws_size is fixed across calls)
    int chb;
    if      (ws_size >= FIXED_SZ + 512ull * PER_CHB) chb = 512;
    else if (ws_size >= FIXED_SZ + 256ull * PER_CHB) chb = 256;
    else if (ws_size >= FIXED_SZ + 128ull * PER_CHB) chb = 128;
    else return;
    const int nch = NB / chb;
    const int crows = chb * S3;
    const int chr = chb * TT;

    const int*   label = (const int*)d_in[0];
    const int*   wav1  = (const int*)d_in[1];
    const int*   wav2  = (const int*)d_in[2];
    const float* el    = (const float*)d_in[3];
    const float* e1    = (const float*)d_in[4];
    const float* e2    = (const float*)d_in[5];
    const float* ln1g  = (const float*)d_in[6];
    const float* ln1b  = (const float*)d_in[7];
    const float* ln2g  = (const float*)d_in[8];
    const float* ln2b  = (const float*)d_in[9];
    const float* Wq    = (const float*)d_in[10];
    const float* bq    = (const float*)d_in[11];
    const float* Wk    = (const float*)d_in[12];
    const float* bk    = (const float*)d_in[13];
    const float* Wv    = (const float*)d_in[14];
    const float* bv    = (const float*)d_in[15];
    const float* Wp    = (const float*)d_in[16];
    const float* bp    = (const float*)d_in[17];
    const float* W1    = (const float*)d_in[18];
    const float* b1    = (const float*)d_in[19];
    const float* W2    = (const float*)d_in[20];
    const float* b2    = (const float*)d_in[21];
    const float* o1W1  = (const float*)d_in[22];
    const float* o1b1  = (const float*)d_in[23];
    const float* o1W2  = (const float*)d_in[24];
    const float* o1b2  = (const float*)d_in[25];
    const float* o2W1  = (const float*)d_in[26];
    const float* o2b1  = (const float*)d_in[27];
    const float* o2W2  = (const float*)d_in[28];
    const float* o2b2  = (const float*)d_in[29];

    char* ws = (char*)d_ws;
    __bf16* WT    = (__bf16*)(ws + WT_OFF);
    __bf16* Wc1T  = (__bf16*)(ws + WC1T_OFF);
    __bf16* Wc2T  = (__bf16*)(ws + WC2T_OFF);
    float*  bc1   = (float*)(ws + BC1_OFF);
    float*  bc2   = (float*)(ws + BC2_OFF);
    float*  bqkv  = (float*)(ws + BQKV_OFF);
    float*  lossb = (float*)(ws + LOSS_OFF);
    __bf16* X     = (__bf16*)(ws + FIXED_SZ);
    __bf16* Hb    = (__bf16*)(ws + FIXED_SZ + (size_t)chb * 135168ull);
    char*   AR    = ws + FIXED_SZ + (size_t)chb * 270336ull;
    // prep temps alias the chunk arena (used only before the chunk loop)
    __bf16* o1W2T = (__bf16*)(AR + 0);
    __bf16* o2W2T = (__bf16*)(AR + 1572864);
    __bf16* o1W1b = (__bf16*)(AR + 3145728);
    __bf16* o2W1b = (__bf16*)(AR + 3932160);
    // per-chunk views
    __bf16* qkvb    = (__bf16*)AR;            // [crows][1536]
    __bf16* yb_     = Hb;                     // y aliases Hb (free after qkv gemm)
    __bf16* hidden  = (__bf16*)AR;
    __bf16* logitsB = (__bf16*)AR;            // bf16 logits [chr][VP]
    float*  outF    = (float*)d_out;

    dim3 tb(32, 8);
    // per-layer weight transposes (z = layer); q,k,v contiguous -> fused [1536,512]
    transpose_cast<<<dim3(16, 16, NL), tb, 0, stream>>>(Wq, WT + 0,       CC, CC, CC, (long long)CC * CC, (long long)LAYER_WELEMS);
    transpose_cast<<<dim3(16, 16, NL), tb, 0, stream>>>(Wk, WT + 262144,  CC, CC, CC, (long long)CC * CC, (long long)LAYER_WELEMS);
    transpose_cast<<<dim3(16, 16, NL), tb, 0, stream>>>(Wv, WT + 524288,  CC, CC, CC, (long long)CC * CC, (long long)LAYER_WELEMS);
    transpose_cast<<<dim3(16, 16, NL), tb, 0, stream>>>(Wp, WT + 786432,  CC, CC, CC, (long long)CC * CC, (long long)LAYER_WELEMS);
    transpose_cast<<<dim3(16, 64, NL), tb, 0, stream>>>(W1, WT + 1048576, CC, HID, HID, (long long)CC * HID, (long long)LAYER_WELEMS);
    transpose_cast<<<dim3(64, 16, NL), tb, 0, stream>>>(W2, WT + 2097152, HID, CC, CC, (long long)HID * CC, (long long)LAYER_WELEMS);
    // head weight prep
    transpose_cast<<<dim3(24, 32, 1), tb, 0, stream>>>(o1W2, o1W2T, OH, NV, VP, 0, 0);
    transpose_cast<<<dim3(24, 32, 1), tb, 0, stream>>>(o2W2, o2W2T, OH, NV, VP, 0, 0);
    cast_k<<<(CC * OH + 255) / 256, 256, 0, stream>>>(o1W1, o1W1b, CC * OH);
    cast_k<<<(CC * OH + 255) / 256, 256, 0, stream>>>(o2W1, o2W1b, CC * OH);
    // WcT[VP,CC] = collapsed head weight (K=768)
    gemm_bt<OH, 0, __bf16, float><<<dim3(4, 8), 256, 0, stream>>>(o1W2T, o1W1b, nullptr, nullptr, Wc1T, VP, CC, 0);
    gemm_bt<OH, 0, __bf16, float><<<dim3(4, 8), 256, 0, stream>>>(o2W2T, o2W1b, nullptr, nullptr, Wc2T, VP, CC, 0);
    combo_bias<<<VP, 256, 0, stream>>>(o1b1, o1W2, o1b2, bc1);
    combo_bias<<<VP, 256, 0, stream>>>(o2b1, o2W2, o2b2, bc2);
    build_bqkv<<<(NL * QKVN + 255) / 256, 256, 0, stream>>>(bq, bk, bv, bqkv);

    for (int c = 0; c < nch; ++c) {
        int b0 = c * chb;
        embed_k<<<crows, 128, 0, stream>>>(label, wav1, wav2, el, e1, e2, X, b0);

        for (int l = 0; l < NL; ++l) {
            const __bf16* WqkvT = WT + (size_t)l * LAYER_WELEMS;          // [1536,512]
            const __bf16* WpT   = WT + (size_t)l * LAYER_WELEMS + 786432;
            const __bf16* W1T   = WT + (size_t)l * LAYER_WELEMS + 1048576;
            const __bf16* W2T   = WT + (size_t)l * LAYER_WELEMS + 2097152;

            ln3_k<<<crows / 4, 256, 0, stream>>>(X, ln1g + l * 3 * CC, ln1b + l * 3 * CC, Hb);
            gemm_bt<CC, 1, __bf16, float><<<dim3(QKVN / 128, crows / 128), 256, 0, stream>>>(Hb, WqkvT, bqkv + l * QKVN, nullptr, qkvb, crows, QKVN, 0);
            attn_k<<<chb * NH, 256, 0, stream>>>(qkvb, yb_);
            gemm_bt<CC, 3, __bf16, __bf16><<<dim3(4, crows / 128), 256, 0, stream>>>(yb_, WpT, bp + l * CC, X, X, crows, CC, 0);
            ln3_k<<<crows / 4, 256, 0, stream>>>(X, ln2g + l * 3 * CC, ln2b + l * 3 * CC, Hb);
            gemm_bt<CC, 5, __bf16, float><<<dim3(16, crows / 128), 256, 0, stream>>>(Hb, W1T, b1 + l * HID, nullptr, hidden, crows, HID, 0);
            gemm_bt<HID, 3, __bf16, __bf16><<<dim3(4, crows / 128), 256, 0, stream>>>(hidden, W2T, b2 + l * CC, X, X, crows, CC, 0);
        }

        // head 1: gathered-A GEMM straight from X (seg offset 44), bf16 logits
        gemm_bt<CC, 9, __bf16, float><<<dim3(VP / 128, chr / 128), 256, 0, stream>>>(X, Wc1T, bc1, nullptr, logitsB, chr, VP, TT);
        ce_k<<<chr / 4, 256, 0, stream>>>(logitsB, wav1 + b0 * 45, lossb + c * chr);
        // head 2 (seg offset 88)
        gemm_bt<CC, 9, __bf16, float><<<dim3(VP / 128, chr / 128), 256, 0, stream>>>(X, Wc2T, bc2, nullptr, logitsB, chr, VP, 2 * TT);
        ce_k<<<chr / 4, 256, 0, stream>>>(logitsB, wav2 + b0 * 45, lossb + HROWS + c * chr);
    }

    ce_sum<<<1, 256, 0, stream>>>(lossb, outF);
}